// Round 15
// baseline (485.266 us; speedup 1.0000x reference)
//
#include <hip/hip_runtime.h>
#include <hip/hip_fp16.h>

constexpr int N    = 100000;
constexpr int E    = 1600000;
constexpr int FIN  = 9;
constexpr int OUTF = 6;
constexpr int G    = 1024;
constexpr int NPB  = 256;                    // nodes per bucket
constexpr int NB   = (N + NPB - 1) / NPB;    // 391 buckets
constexpr int CH   = 2048;                   // edges per chunk
constexpr int NCH  = (E + CH - 1) / CH;      // 782
constexpr int BCAP = 4864;                   // arena slots/bucket (Poisson(4096)+12 sigma)
constexpr int CBCAP= BCAP + NPB + 8;         // csr slots/bucket = 5128
constexpr int EBUF = 5888;                   // passB LDS edge stash (>= BCAP)
constexpr int ZCNT = 256 + G * 64;           // stats0+stats1+pool floats to zero

typedef _Float16 f16x8 __attribute__((ext_vector_type(8)));
typedef float    f32x4 __attribute__((ext_vector_type(4)));

__device__ __forceinline__ void atomAddF(float* p, float v) { unsafeAtomicAdd(p, v); }

// ---- init: arena cursors + zero stats/pool + x -> fp16 table ----
__global__ __launch_bounds__(256) void initK(int* __restrict__ cursor, float* __restrict__ zeros,
    const float* __restrict__ x, __half* __restrict__ x9)
{
    int i = blockIdx.x * 256 + threadIdx.x;
    if (i < NB) cursor[i] = i * BCAP;
    if (i < ZCNT) zeros[i] = 0.f;
    if (i < N * FIN) x9[i] = __float2half(x[i]);
}

// ---- CSR build pass 1: scatter packed edges (src | dloc<<24, w) into fixed-stride arena ----
__global__ __launch_bounds__(256) void passA(const int* __restrict__ src, const int* __restrict__ dst,
    const float* __restrict__ ew, int* __restrict__ cursor, int2* __restrict__ bucketed)
{
    __shared__ int h[NB];
    __shared__ int hb[NB];
    int t = threadIdx.x;
    for (int i = t; i < NB; i += 256) h[i] = 0;
    __syncthreads();
    int base = blockIdx.x * CH;
    int myS[8], myD[8], rk[8]; float myW[8];
#pragma unroll
    for (int i = 0; i < 8; i++) {
        int e = base + i * 256 + t;
        if (e < E) {
            myS[i] = src[e]; myD[i] = dst[e]; myW[i] = ew[e];
            rk[i] = atomicAdd(&h[myD[i] >> 8], 1);
        } else myD[i] = -1;
    }
    __syncthreads();
    for (int i = t; i < NB; i += 256) hb[i] = h[i] ? atomicAdd(&cursor[i], h[i]) : 0;
    __syncthreads();
#pragma unroll
    for (int i = 0; i < 8; i++) if (myD[i] >= 0) {
        int packed = myS[i] | ((myD[i] & 255) << 24);
        bucketed[hb[myD[i] >> 8] + rk[i]] = make_int2(packed, __float_as_int(myW[i]));
    }
}

// ---- CSR build pass 2: per-bucket local CSR (LDS stash), even-aligned node regions ----
__global__ __launch_bounds__(NPB) void passB(const int* __restrict__ cursor,
    const int2* __restrict__ bucketed, int* __restrict__ ebeg, int* __restrict__ eend,
    int2* __restrict__ csr)
{
    __shared__ int2 ebuf[EBUF];
    __shared__ int cl[NPB], sa[NPB], sb[NPB], curs[NPB];
    int b = blockIdx.x, t = threadIdx.x;
    int node0 = b * NPB;
    int nnode = min(NPB, N - node0);
    int cnt = cursor[b] - b * BCAP;
    int abase = b * BCAP;
    int base = b * CBCAP;
    bool fits = (cnt <= EBUF);
    cl[t] = 0;
    __syncthreads();
    for (int e = t; e < cnt; e += NPB) {
        int2 r = bucketed[abase + e];
        if (fits) ebuf[e] = r;
        atomicAdd(&cl[((unsigned)r.x) >> 24], 1);
    }
    __syncthreads();
    int deg = cl[t];
    int pc = (deg + 1) & ~1;
    int* cur = sa; int* nxt = sb;
    cur[t] = pc;
    __syncthreads();
    for (int o = 1; o < NPB; o <<= 1) {
        int v = cur[t];
        if (t >= o) v += cur[t - o];
        nxt[t] = v;
        __syncthreads();
        int* tmp = cur; cur = nxt; nxt = tmp;
    }
    int off = cur[t] - pc;
    if (t < nnode) { ebeg[node0 + t] = base + off; eend[node0 + t] = base + off + deg; }
    curs[t] = off;
    __syncthreads();
    for (int e = t; e < cnt; e += NPB) {
        int2 r = fits ? ebuf[e] : bucketed[abase + e];
        int dl = ((unsigned)r.x) >> 24;
        int pos = base + atomicAdd(&curs[dl], 1);
        csr[pos] = make_int2(r.x & 0x00FFFFFF, r.y);
    }
    __syncthreads();
    if (t < nnode && (deg & 1)) csr[base + off + deg] = make_int2(0, 0);   // w=0 pad
    if (t < 4) csr[base + cur[NPB - 1] + t] = make_int2(0, 0);             // tail pads
}

// ---- weight prep: Wt[c][k] fp16 for layers 1,2 ----
__global__ __launch_bounds__(256) void wprep(const float* __restrict__ Wrel1, const float* __restrict__ Wroot1,
    const float* __restrict__ Wrel2, const float* __restrict__ Wroot2, __half* __restrict__ Wt)
{
    int i = blockIdx.x * 256 + threadIdx.x;      // over 2*128*64 = 16384
    int layer = i >> 13, r = i & 8191;
    int c = r >> 6, k = r & 63;
    const float* Wrel = layer ? Wrel2 : Wrel1;
    const float* Wroot = layer ? Wroot2 : Wroot1;
    float v = (c < 64) ? Wrel[k * 64 + c] : Wroot[k * 64 + (c - 64)];
    Wt[i] = __float2half(v);
}

// ---- FUSED layer 0: 9-dim pipelined gather + projection + BN stats ----
// gather phase: lane = es*16 + fc; projection phase: lane = output channel j.
__global__ __launch_bounds__(256) void g9proj(const __half* __restrict__ x9,
    const int2* __restrict__ csr, const int* __restrict__ ebeg, const int* __restrict__ eend,
    const float* __restrict__ x, const float* __restrict__ Wrel, const float* __restrict__ Wroot,
    const float* __restrict__ bias, __half* __restrict__ H0, float* __restrict__ stats)
{
    int t = threadIdx.x, lane = t & 63;
    int es = lane >> 4, fc = min(lane & 15, FIN - 1);
    float wrel[FIN], wroot[FIN];
#pragma unroll
    for (int k = 0; k < FIN; k++) { wrel[k] = Wrel[k * 64 + lane]; wroot[k] = Wroot[k * 64 + lane]; }
    float bj = bias[lane];
    float s1 = 0.f, s2 = 0.f;
    int wv = (blockIdx.x * blockDim.x + t) >> 6;
    int nw = (gridDim.x * blockDim.x) >> 6;
    for (int n = wv; n < N; n += nw) {
        int beg = ebeg[n], end = eend[n];
        int last = end - 1;
        int2 eA0 = csr[min(beg + es,      last)];
        int2 eB0 = csr[min(beg + 4 + es,  last)];
        int2 eA1 = csr[min(beg + 8 + es,  last)];
        int2 eB1 = csr[min(beg + 12 + es, last)];
        __half xA = x9[(size_t)eA0.x * FIN + fc];
        __half xB = x9[(size_t)eB0.x * FIN + fc];
        float a0 = 0.f, a1 = 0.f;
        for (int k = beg; k < end; k += 8) {
            int2 eA2 = csr[min(k + 16 + es, last)];
            int2 eB2 = csr[min(k + 20 + es, last)];
            __half nxA = x9[(size_t)eA1.x * FIN + fc];
            __half nxB = x9[(size_t)eB1.x * FIN + fc];
            float wA = (k + es     < end) ? __int_as_float(eA0.y) : 0.f;
            float wB = (k + 4 + es < end) ? __int_as_float(eB0.y) : 0.f;
            a0 = fmaf(wA, __half2float(xA), a0);
            a1 = fmaf(wB, __half2float(xB), a1);
            eA0 = eA1; eB0 = eB1; eA1 = eA2; eB1 = eB2;
            xA = nxA; xB = nxB;
        }
        float r = a0 + a1;
        r += __shfl(r, lane ^ 16, 64);
        r += __shfl(r, lane ^ 32, 64);
        // r on lane k (k<9) = agg9[k]; project to 64 channels
        float h = bj;
#pragma unroll
        for (int k2 = 0; k2 < FIN; k2++) {
            float ak = __shfl(r, k2, 64);
            h = fmaf(ak, wrel[k2], h);
            h = fmaf(x[(size_t)n * FIN + k2], wroot[k2], h);
        }
        H0[(size_t)n * 64 + lane] = __float2half(h);
        s1 += h; s2 += h * h;
    }
    __shared__ float sred[256];
    sred[t] = s1; __syncthreads();
    if (t < 64) atomAddF(&stats[t], sred[t] + sred[t+64] + sred[t+128] + sred[t+192]);
    __syncthreads();
    sred[t] = s2; __syncthreads();
    if (t < 64) atomAddF(&stats[64 + t], sred[t] + sred[t+64] + sred[t+128] + sred[t+192]);
}

// ---- MFMA projection w/ fused BN+ReLU on input ----
__global__ __launch_bounds__(256) void projm(const __half* __restrict__ Hin, const __half* __restrict__ Wt,
    const float* __restrict__ bias, const float* __restrict__ stats,
    const float* __restrict__ gam, const float* __restrict__ bet,
    __half* __restrict__ P, __half* __restrict__ Hout)
{
    int t = threadIdx.x, lane = t & 63;
    int wv = blockIdx.x * 4 + (t >> 6);
    int nw = gridDim.x * 4;
    int n16 = lane & 15, quad = lane >> 4;
    constexpr float invN = 1.0f / (float)N;
    float sc[16], sh[16];
#pragma unroll
    for (int jj = 0; jj < 16; jj++) {
        int k = (jj < 8) ? (quad * 8 + jj) : (32 + quad * 8 + (jj - 8));
        float m = stats[k] * invN;
        float v = stats[64 + k] * invN - m * m;
        sc[jj] = gam[k] * rsqrtf(v + 1e-5f);
        sh[jj] = bet[k] - m * sc[jj];
    }
    f16x8 bf[8][2];
#pragma unroll
    for (int ct = 0; ct < 8; ct++)
#pragma unroll
        for (int kh = 0; kh < 2; kh++)
            bf[ct][kh] = *(const f16x8*)(Wt + (size_t)(ct * 16 + n16) * 64 + kh * 32 + quad * 8);
    float bcol[4];
#pragma unroll
    for (int i = 0; i < 4; i++) bcol[i] = bias[i * 16 + n16];
    const int NT = N / 16;
    for (int tile = wv; tile < NT; tile += nw) {
        int n0 = tile * 16;
        f16x8 r0 = *(const f16x8*)(Hin + (size_t)(n0 + n16) * 64 + quad * 8);
        f16x8 r1 = *(const f16x8*)(Hin + (size_t)(n0 + n16) * 64 + 32 + quad * 8);
        f16x8 a0, a1;
#pragma unroll
        for (int jj = 0; jj < 8; jj++) {
            a0[jj] = (_Float16)fmaxf(fmaf((float)r0[jj], sc[jj],     sh[jj]),     0.f);
            a1[jj] = (_Float16)fmaxf(fmaf((float)r1[jj], sc[jj + 8], sh[jj + 8]), 0.f);
        }
        f32x4 acc[8];
#pragma unroll
        for (int ct = 0; ct < 8; ct++) {
            f32x4 c = {0.f, 0.f, 0.f, 0.f};
            c = __builtin_amdgcn_mfma_f32_16x16x32_f16(a0, bf[ct][0], c, 0, 0, 0);
            c = __builtin_amdgcn_mfma_f32_16x16x32_f16(a1, bf[ct][1], c, 0, 0, 0);
            acc[ct] = c;
        }
#pragma unroll
        for (int ct = 0; ct < 8; ct++) {
#pragma unroll
            for (int r = 0; r < 4; r++) {
                int n = n0 + quad * 4 + r;
                if (ct < 4) P[(size_t)n * 64 + ct * 16 + n16] = __float2half(acc[ct][r]);
                else Hout[(size_t)n * 64 + (ct - 4) * 16 + n16] = __float2half(acc[ct][r] + bcol[ct - 4]);
            }
        }
    }
}

// ---- gather-aggregate, 3-STAGE pipeline: csr k+6 prefetch, P k+4 issue, consume k ----
// Weights extracted at P-issue time so src indices die early (register relief).
template<int EPI>   // 0: write H + BN stats; 1: pool atomics
__global__ __launch_bounds__(256) void gather(const __half* __restrict__ P, __half* H,
    const int2* __restrict__ csr, const int* __restrict__ ebeg, const int* __restrict__ eend,
    float* __restrict__ stats, const int* __restrict__ batch, float* __restrict__ pool)
{
    int t = threadIdx.x, lane = t & 63;
    int wv = (blockIdx.x * blockDim.x + t) >> 6;
    int nw = (gridDim.x * blockDim.x) >> 6;
    float s1 = 0.f, s2 = 0.f;
    const int NPAIR = N / 2;
    for (int pr = wv; pr < NPAIR; pr += nw) {
        int n0 = 2 * pr, n1 = n0 + 1;
        int b0 = ebeg[n0], m0 = (eend[n0] - b0 + 1) >> 1;
        int b1 = ebeg[n1], m1 = (eend[n1] - b1 + 1) >> 1;
        const int4* q0 = (const int4*)csr + (b0 >> 1);
        const int4* q1 = (const int4*)csr + (b1 >> 1);
        int c0 = max(m0 - 1, 0), c1 = max(m1 - 1, 0);
        float x0 = __half2float(H[(size_t)n0 * 64 + lane]);
        float x1 = __half2float(H[(size_t)n1 * 64 + lane]);
        int mm = max(m0, m1);
        // ---- stage 0 (iter 0): csr + P issue + weights ----
        int4 qa = q0[0], qb = q0[min(1, c0)], qc = q1[0], qd = q1[min(1, c1)];
        __half v0a0 = P[(size_t)qa.x * 64 + lane], v0a1 = P[(size_t)qa.z * 64 + lane];
        __half v0b0 = P[(size_t)qb.x * 64 + lane], v0b1 = P[(size_t)qb.z * 64 + lane];
        __half v0c0 = P[(size_t)qc.x * 64 + lane], v0c1 = P[(size_t)qc.z * 64 + lane];
        __half v0d0 = P[(size_t)qd.x * 64 + lane], v0d1 = P[(size_t)qd.z * 64 + lane];
        float w0a = (0 < m0) ? __int_as_float(qa.y) : 0.f, w0A = (0 < m0) ? __int_as_float(qa.w) : 0.f;
        float w0b = (1 < m0) ? __int_as_float(qb.y) : 0.f, w0B = (1 < m0) ? __int_as_float(qb.w) : 0.f;
        float w0c = (0 < m1) ? __int_as_float(qc.y) : 0.f, w0C = (0 < m1) ? __int_as_float(qc.w) : 0.f;
        float w0d = (1 < m1) ? __int_as_float(qd.y) : 0.f, w0D = (1 < m1) ? __int_as_float(qd.w) : 0.f;
        // ---- stage 1 (iter 2): csr + P issue + weights ----
        qa = q0[min(2, c0)]; qb = q0[min(3, c0)]; qc = q1[min(2, c1)]; qd = q1[min(3, c1)];
        __half v1a0 = P[(size_t)qa.x * 64 + lane], v1a1 = P[(size_t)qa.z * 64 + lane];
        __half v1b0 = P[(size_t)qb.x * 64 + lane], v1b1 = P[(size_t)qb.z * 64 + lane];
        __half v1c0 = P[(size_t)qc.x * 64 + lane], v1c1 = P[(size_t)qc.z * 64 + lane];
        __half v1d0 = P[(size_t)qd.x * 64 + lane], v1d1 = P[(size_t)qd.z * 64 + lane];
        float w1a = (2 < m0) ? __int_as_float(qa.y) : 0.f, w1A = (2 < m0) ? __int_as_float(qa.w) : 0.f;
        float w1b = (3 < m0) ? __int_as_float(qb.y) : 0.f, w1B = (3 < m0) ? __int_as_float(qb.w) : 0.f;
        float w1c = (2 < m1) ? __int_as_float(qc.y) : 0.f, w1C = (2 < m1) ? __int_as_float(qc.w) : 0.f;
        float w1d = (3 < m1) ? __int_as_float(qd.y) : 0.f, w1D = (3 < m1) ? __int_as_float(qd.w) : 0.f;
        // ---- stage 2 (iter 4): csr held full, P issued inside loop ----
        int4 Qa = q0[min(4, c0)], Qb = q0[min(5, c0)], Qc = q1[min(4, c1)], Qd = q1[min(5, c1)];
        float a0 = 0.f, a1 = 0.f, a2 = 0.f, a3 = 0.f;
        float a4 = 0.f, a5 = 0.f, a6 = 0.f, a7 = 0.f;
        for (int k = 0; k < mm; k += 2) {
            // csr prefetch iter k+6
            int4 Na = q0[min(k + 6, c0)], Nb = q0[min(k + 7, c0)];
            int4 Nc = q1[min(k + 6, c1)], Nd = q1[min(k + 7, c1)];
            // P issue for iter k+4 from Q*, extract weights
            __half v2a0 = P[(size_t)Qa.x * 64 + lane], v2a1 = P[(size_t)Qa.z * 64 + lane];
            __half v2b0 = P[(size_t)Qb.x * 64 + lane], v2b1 = P[(size_t)Qb.z * 64 + lane];
            __half v2c0 = P[(size_t)Qc.x * 64 + lane], v2c1 = P[(size_t)Qc.z * 64 + lane];
            __half v2d0 = P[(size_t)Qd.x * 64 + lane], v2d1 = P[(size_t)Qd.z * 64 + lane];
            float w2a = (k + 4 < m0) ? __int_as_float(Qa.y) : 0.f, w2A = (k + 4 < m0) ? __int_as_float(Qa.w) : 0.f;
            float w2b = (k + 5 < m0) ? __int_as_float(Qb.y) : 0.f, w2B = (k + 5 < m0) ? __int_as_float(Qb.w) : 0.f;
            float w2c = (k + 4 < m1) ? __int_as_float(Qc.y) : 0.f, w2C = (k + 4 < m1) ? __int_as_float(Qc.w) : 0.f;
            float w2d = (k + 5 < m1) ? __int_as_float(Qd.y) : 0.f, w2D = (k + 5 < m1) ? __int_as_float(Qd.w) : 0.f;
            // consume stage 0
            a0 = fmaf(w0a, __half2float(v0a0), a0); a1 = fmaf(w0A, __half2float(v0a1), a1);
            a2 = fmaf(w0b, __half2float(v0b0), a2); a3 = fmaf(w0B, __half2float(v0b1), a3);
            a4 = fmaf(w0c, __half2float(v0c0), a4); a5 = fmaf(w0C, __half2float(v0c1), a5);
            a6 = fmaf(w0d, __half2float(v0d0), a6); a7 = fmaf(w0D, __half2float(v0d1), a7);
            // rotate weights + P values + csr
            w0a = w1a; w0A = w1A; w0b = w1b; w0B = w1B; w0c = w1c; w0C = w1C; w0d = w1d; w0D = w1D;
            w1a = w2a; w1A = w2A; w1b = w2b; w1B = w2B; w1c = w2c; w1C = w2C; w1d = w2d; w1D = w2D;
            v0a0 = v1a0; v0a1 = v1a1; v0b0 = v1b0; v0b1 = v1b1;
            v0c0 = v1c0; v0c1 = v1c1; v0d0 = v1d0; v0d1 = v1d1;
            v1a0 = v2a0; v1a1 = v2a1; v1b0 = v2b0; v1b1 = v2b1;
            v1c0 = v2c0; v1c1 = v2c1; v1d0 = v2d0; v1d1 = v2d1;
            Qa = Na; Qb = Nb; Qc = Nc; Qd = Nd;
        }
        float r0 = x0 + ((a0 + a2) + (a1 + a3));
        float r1 = x1 + ((a4 + a6) + (a5 + a7));
        if constexpr (EPI == 0) {
            H[(size_t)n0 * 64 + lane] = __float2half(r0);
            H[(size_t)n1 * 64 + lane] = __float2half(r1);
            s1 += r0 + r1; s2 += r0 * r0 + r1 * r1;
        } else {
            atomAddF(&pool[batch[n0] * 64 + lane], r0);
            atomAddF(&pool[batch[n1] * 64 + lane], r1);
        }
    }
    if constexpr (EPI == 0) {
        __shared__ float sred[256];
        sred[t] = s1; __syncthreads();
        if (t < 64) atomAddF(&stats[t], sred[t] + sred[t+64] + sred[t+128] + sred[t+192]);
        __syncthreads();
        sred[t] = s2; __syncthreads();
        if (t < 64) atomAddF(&stats[64 + t], sred[t] + sred[t+64] + sred[t+128] + sred[t+192]);
    }
}

// ---- head: mean-pool finalize + 2-layer MLP ----
__global__ __launch_bounds__(64) void head(const float* __restrict__ pool,
    const int* __restrict__ batch, const float* __restrict__ Wl1, const float* __restrict__ bl1,
    const float* __restrict__ Wl2, const float* __restrict__ bl2, float* __restrict__ out)
{
    int g = blockIdx.x, t = threadIdx.x;
    __shared__ float sp[64];
    __shared__ float sz[64];
    __shared__ int scnt;
    if (t == 0) {
        int lo = 0, hi = N;
        while (lo < hi) { int m = (lo + hi) >> 1; if (batch[m] < g) lo = m + 1; else hi = m; }
        int lo2 = lo, hi2 = N;
        while (lo2 < hi2) { int m = (lo2 + hi2) >> 1; if (batch[m] < g + 1) lo2 = m + 1; else hi2 = m; }
        scnt = lo2 - lo;
    }
    __syncthreads();
    float cnt = fmaxf((float)scnt, 1.0f);
    sp[t] = pool[g * 64 + t] / cnt;
    __syncthreads();
    float acc = bl1[t];
#pragma unroll
    for (int k = 0; k < 64; k++) acc = fmaf(sp[k], Wl1[k * 64 + t], acc);
    sz[t] = fmaxf(acc, 0.f);
    __syncthreads();
    if (t < OUTF) {
        float o = bl2[t];
#pragma unroll
        for (int k = 0; k < 64; k++) o = fmaf(sz[k], Wl2[k * OUTF + t], o);
        out[g * OUTF + t] = o;
    }
}

extern "C" void kernel_launch(void* const* d_in, const int* in_sizes, int n_in,
                              void* d_out, int out_size, void* d_ws, size_t ws_size,
                              hipStream_t stream)
{
    const float* x     = (const float*)d_in[0];
    const int*   ei    = (const int*)d_in[1];
    const float* ew    = (const float*)d_in[2];
    const int*   batch = (const int*)d_in[3];
    const float* Wrel0 = (const float*)d_in[4];
    const float* Wroot0= (const float*)d_in[5];
    const float* b0    = (const float*)d_in[6];
    const float* Wrel1 = (const float*)d_in[7];
    const float* Wroot1= (const float*)d_in[8];
    const float* b1    = (const float*)d_in[9];
    const float* Wrel2 = (const float*)d_in[10];
    const float* Wroot2= (const float*)d_in[11];
    const float* b2    = (const float*)d_in[12];
    const float* g0    = (const float*)d_in[13];
    const float* be0   = (const float*)d_in[14];
    const float* g1    = (const float*)d_in[15];
    const float* be1   = (const float*)d_in[16];
    const float* Wl1   = (const float*)d_in[17];
    const float* bl1   = (const float*)d_in[18];
    const float* Wl2   = (const float*)d_in[19];
    const float* bl2   = (const float*)d_in[20];
    const int* srcI = ei;
    const int* dstI = ei + E;

    __half* Ha     = (__half*)d_ws;                    // N*64 fp16
    __half* Hb     = Ha + (size_t)N * 64;              // N*64 fp16
    __half* P      = Hb + (size_t)N * 64;              // N*64 fp16
    int2*   csr    = (int2*)(P + (size_t)N * 64);      // NB*CBCAP int2 (~16 MB)
    int*    ebeg   = (int*)(csr + (size_t)NB * CBCAP); // N
    int*    eend   = ebeg + N;                         // N
    int*    cursor = eend + N;                         // NB
    float*  stats0 = (float*)(cursor + NB);            // 128 -- zero block start
    float*  stats1 = stats0 + 128;                     // 128
    float*  pool   = stats1 + 128;                     // G*64 -- zero block end
    __half* Wt1    = (__half*)(pool + G * 64);         // 128*64
    __half* Wt2    = Wt1 + 128 * 64;                   // 128*64
    __half* x9     = Wt2 + 128 * 64;                   // N*9 fp16 (1.8 MB)
    int2*   bucketed = (int2*)Ha;                      // NB*BCAP int2 = 15.2MB, aliases Ha+Hb

    // ---- init + CSR build (bucketed arena, by dst) ----
    initK<<<(N * FIN + 255) / 256, 256, 0, stream>>>(cursor, stats0, x, x9);
    passA<<<NCH, 256, 0, stream>>>(srcI, dstI, ew, cursor, bucketed);
    passB<<<NB, NPB, 0, stream>>>(cursor, bucketed, ebeg, eend, csr);
    wprep<<<64, 256, 0, stream>>>(Wrel1, Wroot1, Wrel2, Wroot2, Wt1);

    // ---- layer 0: fused 9-dim gather + projection + BN stats ----
    g9proj<<<2048, 256, 0, stream>>>(x9, csr, ebeg, eend, x, Wrel0, Wroot0, b0, Ha, stats0);

    // ---- layer 1 (BN0+ReLU fused into projm input) ----
    projm<<<1024, 256, 0, stream>>>(Ha, Wt1, b1, stats0, g0, be0, P, Hb);
    gather<0><<<2048, 256, 0, stream>>>(P, Hb, csr, ebeg, eend, stats1, nullptr, nullptr);

    // ---- layer 2 + pooling (BN1+ReLU fused into projm input) ----
    projm<<<1024, 256, 0, stream>>>(Hb, Wt2, b2, stats1, g1, be1, P, Ha);
    gather<1><<<2048, 256, 0, stream>>>(P, Ha, csr, ebeg, eend, nullptr, batch, pool);

    // ---- head ----
    head<<<G, 64, 0, stream>>>(pool, batch, Wl1, bl1, Wl2, bl2, (float*)d_out);
}